// Round 14
// baseline (508.795 us; speedup 1.0000x reference)
//
#include <hip/hip_runtime.h>
#include <math.h>

// Problem constants
#define B_   16
#define C_   256
#define T_   4096
#define V_   1024
#define K_   4
#define TPB  64      // tokens per block
#define RFP  260     // padded Rf row stride (floats); 1040 B, 16B-aligned, bank-spread
#define EPS_CAND 2e-4f

constexpr int Z_ELEMS   = B_ * C_ * T_;        // 16777216
constexpr int IDX_ELEMS = B_ * K_ * T_;        // 262144
constexpr int LOSS_OFF  = Z_ELEMS + IDX_ELEMS; // 17039360

typedef _Float16 h8 __attribute__((ext_vector_type(8)));
typedef __fp16   g2 __attribute__((ext_vector_type(2)));   // cvt_pkrtz return type
typedef float    f4 __attribute__((ext_vector_type(4)));

// monotone float<->uint order map: a < b  <=>  fmap(a) < fmap(b) (unsigned)
__device__ __forceinline__ unsigned fmap(float x) {
    unsigned u = __float_as_uint(x);
    return (u & 0x80000000u) ? ~u : (u | 0x80000000u);
}
__device__ __forceinline__ float funmap(unsigned u) {
    return (u & 0x80000000u) ? __uint_as_float(u & 0x7fffffffu) : __uint_as_float(~u);
}

__global__ void rvq_zero_loss(float* out) { out[LOSS_OFF] = 0.0f; }

// ||c||^2 partials, bit-identical chains to rounds 1-13:
// part0 = fma chain over c = 0..63 then 128..191
// part1 = fma chain over c = 64..127 then 192..255
__global__ void rvq_cvnorm(const float* __restrict__ cb, float2* __restrict__ cvw)
{
    int g = blockIdx.x * 256 + threadIdx.x;   // 0..4095 = st*1024 + v
    const float* row = cb + (size_t)g * C_;
    float p0 = 0.f, p1 = 0.f;
    for (int c = 0;   c < 64;  ++c) p0 = fmaf(row[c], row[c], p0);
    for (int c = 128; c < 192; ++c) p0 = fmaf(row[c], row[c], p0);
    for (int c = 64;  c < 128; ++c) p1 = fmaf(row[c], row[c], p1);
    for (int c = 192; c < 256; ++c) p1 = fmaf(row[c], row[c], p1);
    cvw[g] = make_float2(p0, p1);
}

// Codebook -> f16 B-fragments for mfma_f32_16x16x32_f16 (scaled by 16, RN).
// lane l, elem i of tile nt, k-step ks = B[k=ks*32+(l>>4)*8+i][n=nt*16+(l&15)]
// flat h8 index: ((st*64 + nt)*8 + ks)*64 + l
__global__ void rvq_cbf16(const float* __restrict__ cb, _Float16* __restrict__ cbh)
{
    int gid = blockIdx.x * 256 + threadIdx.x;   // 131072 h8 quads
    int l  = gid & 63;
    int ks = (gid >> 6) & 7;
    int nt = (gid >> 9) & 63;
    int st = gid >> 15;
    int v  = nt * 16 + (l & 15);
    int k  = ks * 32 + (l >> 4) * 8;
    const float* src = cb + ((size_t)(st * V_ + v)) * C_ + k;
    float4 c0 = *reinterpret_cast<const float4*>(src);
    float4 c1 = *reinterpret_cast<const float4*>(src + 4);
    h8 o;
    o[0] = (_Float16)(c0.x * 16.0f);
    o[1] = (_Float16)(c0.y * 16.0f);
    o[2] = (_Float16)(c0.z * 16.0f);
    o[3] = (_Float16)(c0.w * 16.0f);
    o[4] = (_Float16)(c1.x * 16.0f);
    o[5] = (_Float16)(c1.y * 16.0f);
    o[6] = (_Float16)(c1.z * 16.0f);
    o[7] = (_Float16)(c1.w * 16.0f);
    reinterpret_cast<h8*>(cbh)[gid] = o;
}

__launch_bounds__(512, 4)
__global__ void rvq_main(const float* __restrict__ z,
                         const float* __restrict__ cb,
                         const float2* __restrict__ cvw,
                         const _Float16* __restrict__ cbh,
                         float* __restrict__ out)
{
    __shared__ float    Rf[TPB][RFP];        // residual fp32, TOKEN-major (66.56 KB)
    __shared__ int      candIdx[TPB][16];    // candidate lists (4 KB); loss scratch at end
    __shared__ float    rnpart[TPB][8];      // ||r||^2 strip partials (2 KB)
    __shared__ unsigned fminI[4][TPB];       // per-pass mapped approx-min (1 KB)
    __shared__ unsigned long long best64[TPB]; // packed (d,idx) select (0.5 KB)
    __shared__ int      candCnt[TPB];
    __shared__ int      bestIdx[TPB];

    const int tid = threadIdx.x;           // 0..511
    const int blk = blockIdx.x;
    const int b   = blk >> 6;
    const int t0  = (blk & 63) * TPB;

    const int w   = tid >> 6;              // wave id = vector stripe (32 vec per pass)
    const int l   = tid & 63;              // lane
    const int ut  = tid & 63;              // update-phase token
    const int ug  = tid >> 6;              // update-phase c-strip (8 x 32)

    const int am   = l & 15;               // m/n within 16-tile
    const int akof = (l >> 4) * 8;         // k sub-block offset (K=32 frag)

    // ---- stage residual tile (token-major fp32) ----
    const float* zb = z + (size_t)b * C_ * T_ + t0;
    for (int j = 0; j < 32; ++j) {
        int c = ug * 32 + j;
        Rf[ut][c] = zb[(size_t)c * T_ + ut];
    }
    __syncthreads();
    // ---- rnpart init (identical chains to rounds 3-13) ----
    {
        float p = 0.f;
        for (int j = 0; j < 32; ++j) { float r = Rf[ut][ug * 32 + j]; p = fmaf(r, r, p); }
        rnpart[ut][ug] = p;
    }
    if (tid < TPB) {
        candCnt[tid] = 0;
        best64[tid]  = ~0ull;
        fminI[0][tid] = 0xFFFFFFFFu;
        fminI[1][tid] = 0xFFFFFFFFu;
        fminI[2][tid] = 0xFFFFFFFFu;
        fminI[3][tid] = 0xFFFFFFFFu;
    }
    __syncthreads();

    float loss_acc = 0.f;

    for (int st = 0; st < K_; ++st) {
        const float* cbs = cb + (size_t)st * V_ * C_;

        // ====== four N-passes; each wave covers 64 tok x 32 vec (acc[4][2]) ======
        for (int p = 0; p < 4; ++p) {
            const int vbase = p * 256 + w * 32;

            f4 acc[4][2];
            #pragma unroll
            for (int mt = 0; mt < 4; ++mt)
                #pragma unroll
                for (int nf = 0; nf < 2; ++nf)
                    acc[mt][nf] = (f4){0.f, 0.f, 0.f, 0.f};

            {
                const h8* cbh8 = reinterpret_cast<const h8*>(cbh);
                const size_t wbase = (size_t)(st * 64 + (vbase >> 4)) * 512 + l;
                #pragma unroll 4
                for (int ks = 0; ks < 8; ++ks) {
                    const int k0 = ks * 32 + akof;
                    h8 af[4];
                    #pragma unroll
                    for (int mt = 0; mt < 4; ++mt) {
                        const int m = mt * 16 + am;
                        f4 x = *reinterpret_cast<const f4*>(&Rf[m][k0]);
                        f4 y = *reinterpret_cast<const f4*>(&Rf[m][k0 + 4]);
                        // RTZ pack-convert: filter-only (phase B exact);
                        // validated bit-identical indices in round-12 run
                        union { h8 v; g2 pk[4]; } u;
                        u.pk[0] = __builtin_amdgcn_cvt_pkrtz(x[0], x[1]);
                        u.pk[1] = __builtin_amdgcn_cvt_pkrtz(x[2], x[3]);
                        u.pk[2] = __builtin_amdgcn_cvt_pkrtz(y[0], y[1]);
                        u.pk[3] = __builtin_amdgcn_cvt_pkrtz(y[2], y[3]);
                        af[mt] = u.v;
                    }
                    #pragma unroll
                    for (int nf = 0; nf < 2; ++nf) {
                        h8 bf = cbh8[wbase + (size_t)nf * 512 + ks * 64];
                        #pragma unroll
                        for (int mt = 0; mt < 4; ++mt)
                            acc[mt][nf] = __builtin_amdgcn_mfma_f32_16x16x32_f16(af[mt], bf, acc[mt][nf], 0, 0, 0);
                    }
                }
            }

            // ---- approx distances d' = cv2 - 0.125*acc ----
            #pragma unroll
            for (int nf = 0; nf < 2; ++nf) {
                int v = vbase + nf * 16 + am;
                float2 pv = cvw[st * V_ + v];
                float cv2 = __fadd_rn(pv.x, pv.y);
                #pragma unroll
                for (int mt = 0; mt < 4; ++mt)
                    #pragma unroll
                    for (int jj = 0; jj < 4; ++jj)
                        acc[mt][nf][jj] = fmaf(acc[mt][nf][jj], -0.125f, cv2);
            }

            // ---- per-wave per-token min -> LDS atomicMin (exact; min has no rounding) ----
            #pragma unroll
            for (int mt = 0; mt < 4; ++mt)
                #pragma unroll
                for (int jj = 0; jj < 4; ++jj) {
                    float m0 = fminf(acc[mt][0][jj], acc[mt][1][jj]);
                    m0 = fminf(m0, __shfl_xor(m0, 1, 16));
                    m0 = fminf(m0, __shfl_xor(m0, 2, 16));
                    m0 = fminf(m0, __shfl_xor(m0, 4, 16));
                    m0 = fminf(m0, __shfl_xor(m0, 8, 16));
                    if (am == 0)
                        atomicMin(&fminI[p][mt * 16 + 4 * (l >> 4) + jj], fmap(m0));
                }
            __syncthreads();   // fminI[p] complete across waves

            // ---- candidate scan & push (pass-local min window; superset) ----
            #pragma unroll
            for (int mt = 0; mt < 4; ++mt)
                #pragma unroll
                for (int jj = 0; jj < 4; ++jj) {
                    int t = mt * 16 + 4 * (l >> 4) + jj;
                    float fthr = funmap(fminI[p][t]) + EPS_CAND;
                    #pragma unroll
                    for (int nf = 0; nf < 2; ++nf)
                        if (acc[mt][nf][jj] <= fthr) {
                            int s = atomicAdd(&candCnt[t], 1);
                            if (s < 16) candIdx[t][s] = vbase + nf * 16 + am;
                        }
                }
            // no trailing barrier: next pass writes only fminI[p+1]/private acc;
            // Rf/cbh read-only here; pushes atomic and order-free
        }
        __syncthreads();   // all candidates in before phase B

        // ---- Phase B: exact fp32-chain distance + packed (d,idx) atomic select ----
        {
            int t = tid & 63, s0 = tid >> 6;
            int nc = candCnt[t]; if (nc > 16) nc = 16;
            for (int s = s0; s < nc; s += 8) {
                int gi = candIdx[t][s];
                const float* crow = cbs + (size_t)gi * C_;
                float dot = 0.f;
                for (int c = 0; c < 256; c += 4) {
                    float4 cr = *reinterpret_cast<const float4*>(crow + c);
                    f4 rv = *reinterpret_cast<const f4*>(&Rf[t][c]);
                    dot = __fadd_rn(dot, __fmul_rn(rv[0], cr.x));
                    dot = __fadd_rn(dot, __fmul_rn(rv[1], cr.y));
                    dot = __fadd_rn(dot, __fmul_rn(rv[2], cr.z));
                    dot = __fadd_rn(dot, __fmul_rn(rv[3], cr.w));
                }
                float2 pv = cvw[st * V_ + gi];
                float cv2 = __fadd_rn(pv.x, pv.y);
                // Rnorm: identical fadd chain over strip partials (as rounds 3-13)
                float Rn = rnpart[t][0];
                #pragma unroll
                for (int k = 1; k < 8; ++k) Rn = __fadd_rn(Rn, rnpart[t][k]);
                float S = __fadd_rn(Rn, cv2);
                float d = __fsub_rn(S, 2.0f * dot);
                unsigned long long key =
                    ((unsigned long long)fmap(d) << 32) | (unsigned)gi;
                atomicMin(&best64[t], key);
            }
        }
        __syncthreads();   // best ready
        if (tid < TPB) {
            int bi = (int)(best64[tid] & 0xFFFFFFFFull);
            bestIdx[tid] = bi;
            out[Z_ELEMS + ((size_t)b * K_ + st) * T_ + t0 + tid] = (float)bi;
            best64[tid]  = ~0ull;            // reset for next stage
            candCnt[tid] = 0;
            fminI[0][tid] = 0xFFFFFFFFu;
            fminI[1][tid] = 0xFFFFFFFFu;
            fminI[2][tid] = 0xFFFFFFFFu;
            fminI[3][tid] = 0xFFFFFFFFu;
        }
        __syncthreads();   // bestIdx ready, resets done

        // ---- update: STE rounding exact (unchanged per-element chains) ----
        {
            const float* q = cbs + (size_t)bestIdx[ut] * C_ + ug * 32;
            float rn = 0.f;
            #pragma unroll
            for (int j4 = 0; j4 < 8; ++j4) {
                int c0 = ug * 32 + 4 * j4;
                float4 qv = *reinterpret_cast<const float4*>(q + 4 * j4);
                f4 rv = *reinterpret_cast<const f4*>(&Rf[ut][c0]);
                float qe[4] = { qv.x, qv.y, qv.z, qv.w };
                f4 nv;
                #pragma unroll
                for (int e = 0; e < 4; ++e) {
                    float r   = rv[e];
                    float qmr = __fsub_rn(qe[e], r);   // sg(q - r)
                    float zq  = __fadd_rn(r, qmr);     // r + sg(q - r)
                    float lt  = __fsub_rn(zq, r);      // sg(zq) - r
                    loss_acc  = fmaf(lt, lt, loss_acc);
                    float rn2 = __fsub_rn(r, zq);      // r - sg(zq)
                    nv[e] = rn2;
                    rn = fmaf(rn2, rn2, rn);
                }
                *reinterpret_cast<f4*>(&Rf[ut][c0]) = nv;
            }
            rnpart[ut][ug] = rn;
        }
        __syncthreads();   // Rf + rnpart ready for next stage
    }

    // ---- epilogue: z_q = z - r_final ----
    {
        float* ob = out + (size_t)b * C_ * T_ + t0;
        for (int j = 0; j < 32; ++j) {
            int c = ug * 32 + j;
            ob[(size_t)c * T_ + ut] = __fsub_rn(zb[(size_t)c * T_ + ut], Rf[ut][c]);
        }
    }

    // ---- loss block-reduce -> atomicAdd (candIdx reused as scratch) ----
    __syncthreads();
    float* lred = reinterpret_cast<float*>(&candIdx[0][0]);   // 1024 floats avail
    lred[tid] = loss_acc;
    __syncthreads();
    if (tid < 256) lred[tid] += lred[tid + 256];
    __syncthreads();
    if (tid < 128) lred[tid] += lred[tid + 128];
    __syncthreads();
    if (tid < 64)  lred[tid] += lred[tid + 64];
    __syncthreads();
    if (tid == 0) {
        float s = 0.f;
        for (int i = 0; i < 64; ++i) s += lred[i];
        atomicAdd(out + LOSS_OFF, s * (1.0f / 67108864.0f));  // / (B*T*C) / K
    }
}

extern "C" void kernel_launch(void* const* d_in, const int* in_sizes, int n_in,
                              void* d_out, int out_size, void* d_ws, size_t ws_size,
                              hipStream_t stream)
{
    const float* z  = (const float*)d_in[0];
    const float* cb = (const float*)d_in[1];
    float* out = (float*)d_out;
    float2*    cvw = (float2*)d_ws;                              // 32 KB
    _Float16*  cbh = (_Float16*)((char*)d_ws + 32768);           // 2 MB

    rvq_zero_loss<<<1, 1, 0, stream>>>(out);
    rvq_cvnorm<<<16, 256, 0, stream>>>(cb, cvw);
    rvq_cbf16<<<512, 256, 0, stream>>>(cb, cbh);
    rvq_main<<<dim3(1024), dim3(512), 0, stream>>>(z, cb, cvw, cbh, out);
}

// Round 15
// 408.371 us; speedup vs baseline: 1.2459x; 1.2459x over previous
//
#include <hip/hip_runtime.h>
#include <math.h>

// Problem constants
#define B_   16
#define C_   256
#define T_   4096
#define V_   1024
#define K_   4
#define TPB  64      // tokens per block
#define RFP  260     // padded Rf row stride (floats); 1040 B, 16B-aligned, bank-spread
#define EPS_CAND 2e-4f

constexpr int Z_ELEMS   = B_ * C_ * T_;        // 16777216
constexpr int IDX_ELEMS = B_ * K_ * T_;        // 262144
constexpr int LOSS_OFF  = Z_ELEMS + IDX_ELEMS; // 17039360

typedef _Float16 h8 __attribute__((ext_vector_type(8)));
typedef float    f4 __attribute__((ext_vector_type(4)));

// monotone float<->uint order map (works for ALL floats incl. negatives):
// a < b  <=>  fmap(a) < fmap(b) (unsigned)
__device__ __forceinline__ unsigned fmap(float x) {
    unsigned u = __float_as_uint(x);
    return (u & 0x80000000u) ? ~u : (u | 0x80000000u);
}
__device__ __forceinline__ float funmap(unsigned u) {
    return (u & 0x80000000u) ? __uint_as_float(u & 0x7fffffffu) : __uint_as_float(~u);
}

__global__ void rvq_zero_loss(float* out) { out[LOSS_OFF] = 0.0f; }

// ||c||^2 partials, bit-identical chains to rounds 1-13:
// part0 = fma chain over c = 0..63 then 128..191
// part1 = fma chain over c = 64..127 then 192..255
__global__ void rvq_cvnorm(const float* __restrict__ cb, float2* __restrict__ cvw)
{
    int g = blockIdx.x * 256 + threadIdx.x;   // 0..4095 = st*1024 + v
    const float* row = cb + (size_t)g * C_;
    float p0 = 0.f, p1 = 0.f;
    for (int c = 0;   c < 64;  ++c) p0 = fmaf(row[c], row[c], p0);
    for (int c = 128; c < 192; ++c) p0 = fmaf(row[c], row[c], p0);
    for (int c = 64;  c < 128; ++c) p1 = fmaf(row[c], row[c], p1);
    for (int c = 192; c < 256; ++c) p1 = fmaf(row[c], row[c], p1);
    cvw[g] = make_float2(p0, p1);
}

// Codebook -> f16 B-fragments for mfma_f32_16x16x32_f16 (scaled by 16, RN).
// lane l, elem i of tile nt, k-step ks = B[k=ks*32+(l>>4)*8+i][n=nt*16+(l&15)]
// flat h8 index: ((st*64 + nt)*8 + ks)*64 + l
__global__ void rvq_cbf16(const float* __restrict__ cb, _Float16* __restrict__ cbh)
{
    int gid = blockIdx.x * 256 + threadIdx.x;   // 131072 h8 quads
    int l  = gid & 63;
    int ks = (gid >> 6) & 7;
    int nt = (gid >> 9) & 63;
    int st = gid >> 15;
    int v  = nt * 16 + (l & 15);
    int k  = ks * 32 + (l >> 4) * 8;
    const float* src = cb + ((size_t)(st * V_ + v)) * C_ + k;
    float4 c0 = *reinterpret_cast<const float4*>(src);
    float4 c1 = *reinterpret_cast<const float4*>(src + 4);
    h8 o;
    o[0] = (_Float16)(c0.x * 16.0f);
    o[1] = (_Float16)(c0.y * 16.0f);
    o[2] = (_Float16)(c0.z * 16.0f);
    o[3] = (_Float16)(c0.w * 16.0f);
    o[4] = (_Float16)(c1.x * 16.0f);
    o[5] = (_Float16)(c1.y * 16.0f);
    o[6] = (_Float16)(c1.z * 16.0f);
    o[7] = (_Float16)(c1.w * 16.0f);
    reinterpret_cast<h8*>(cbh)[gid] = o;
}

__launch_bounds__(512, 4)
__global__ void rvq_main(const float* __restrict__ z,
                         const float* __restrict__ cb,
                         const float2* __restrict__ cvw,
                         const _Float16* __restrict__ cbh,
                         float* __restrict__ out)
{
    __shared__ float    Rf[TPB][RFP];        // residual fp32, TOKEN-major (66.56 KB)
    __shared__ int      candIdx[TPB][16];    // candidate lists (4 KB); loss scratch at end
    __shared__ float    rnpart[TPB][8];      // ||r||^2 strip partials (2 KB)
    __shared__ unsigned fminI[2][TPB];       // per-pass mapped approx-min (0.5 KB)
    __shared__ unsigned long long best64[TPB]; // packed (d,idx) select (0.5 KB)
    __shared__ int      candCnt[TPB];
    __shared__ int      bestIdx[TPB];

    const int tid = threadIdx.x;           // 0..511
    const int blk = blockIdx.x;
    const int b   = blk >> 6;
    const int t0  = (blk & 63) * TPB;

    const int w   = tid >> 6;              // wave id = vector stripe (64 vec per pass)
    const int l   = tid & 63;              // lane
    const int ut  = tid & 63;              // update-phase token
    const int ug  = tid >> 6;              // update-phase c-strip (8 x 32)

    const int am   = l & 15;               // m/n within 16-tile
    const int akof = (l >> 4) * 8;         // k sub-block offset (K=32 frag)

    // ---- stage residual tile (token-major fp32) ----
    const float* zb = z + (size_t)b * C_ * T_ + t0;
    for (int j = 0; j < 32; ++j) {
        int c = ug * 32 + j;
        Rf[ut][c] = zb[(size_t)c * T_ + ut];
    }
    __syncthreads();
    // ---- rnpart init (identical chains to rounds 3-13) ----
    {
        float p = 0.f;
        for (int j = 0; j < 32; ++j) { float r = Rf[ut][ug * 32 + j]; p = fmaf(r, r, p); }
        rnpart[ut][ug] = p;
    }
    if (tid < TPB) {
        candCnt[tid] = 0;
        best64[tid]  = ~0ull;
        fminI[0][tid] = 0xFFFFFFFFu;
        fminI[1][tid] = 0xFFFFFFFFu;
    }
    __syncthreads();

    float loss_acc = 0.f;

    for (int st = 0; st < K_; ++st) {
        const float* cbs = cb + (size_t)st * V_ * C_;

        // ======== two N-passes; each wave covers 64 tok x 64 vec ========
        for (int p = 0; p < 2; ++p) {
            const int vbase = p * 512 + w * 64;

            f4 acc[4][4];
            #pragma unroll
            for (int mt = 0; mt < 4; ++mt)
                #pragma unroll
                for (int nf = 0; nf < 4; ++nf)
                    acc[mt][nf] = (f4){0.f, 0.f, 0.f, 0.f};

            {
                const h8* cbh8 = reinterpret_cast<const h8*>(cbh);
                const size_t wbase = (size_t)(st * 64 + (vbase >> 4)) * 512 + l;
                #pragma unroll 2
                for (int ks = 0; ks < 8; ++ks) {
                    const int k0 = ks * 32 + akof;
                    h8 af[4];
                    #pragma unroll
                    for (int mt = 0; mt < 4; ++mt) {
                        const int m = mt * 16 + am;
                        f4 x = *reinterpret_cast<const f4*>(&Rf[m][k0]);
                        f4 y = *reinterpret_cast<const f4*>(&Rf[m][k0 + 4]);
                        h8 a;
                        a[0] = (_Float16)x[0]; a[1] = (_Float16)x[1];
                        a[2] = (_Float16)x[2]; a[3] = (_Float16)x[3];
                        a[4] = (_Float16)y[0]; a[5] = (_Float16)y[1];
                        a[6] = (_Float16)y[2]; a[7] = (_Float16)y[3];
                        af[mt] = a;
                    }
                    #pragma unroll
                    for (int nf = 0; nf < 4; ++nf) {
                        h8 bf = cbh8[wbase + (size_t)nf * 512 + ks * 64];
                        #pragma unroll
                        for (int mt = 0; mt < 4; ++mt)
                            acc[mt][nf] = __builtin_amdgcn_mfma_f32_16x16x32_f16(af[mt], bf, acc[mt][nf], 0, 0, 0);
                    }
                }
            }

            // ---- approx distances d' = cv2 - 0.125*acc ----
            #pragma unroll
            for (int nf = 0; nf < 4; ++nf) {
                int v = vbase + nf * 16 + am;
                float2 pv = cvw[st * V_ + v];
                float cv2 = __fadd_rn(pv.x, pv.y);
                #pragma unroll
                for (int mt = 0; mt < 4; ++mt)
                    #pragma unroll
                    for (int jj = 0; jj < 4; ++jj)
                        acc[mt][nf][jj] = fmaf(acc[mt][nf][jj], -0.125f, cv2);
            }

            // ---- per-wave per-token min -> LDS atomicMin (exact; min has no rounding) ----
            #pragma unroll
            for (int mt = 0; mt < 4; ++mt)
                #pragma unroll
                for (int jj = 0; jj < 4; ++jj) {
                    float m0 = acc[mt][0][jj];
                    #pragma unroll
                    for (int nf = 1; nf < 4; ++nf) m0 = fminf(m0, acc[mt][nf][jj]);
                    m0 = fminf(m0, __shfl_xor(m0, 1, 16));
                    m0 = fminf(m0, __shfl_xor(m0, 2, 16));
                    m0 = fminf(m0, __shfl_xor(m0, 4, 16));
                    m0 = fminf(m0, __shfl_xor(m0, 8, 16));
                    if (am == 0)
                        atomicMin(&fminI[p][mt * 16 + 4 * (l >> 4) + jj], fmap(m0));
                }
            __syncthreads();   // BAR A/B: fminI[p] complete across waves

            // ---- candidate scan & push (pass-local min window; superset) ----
            // (entry ORDER in candIdx is arbitrary across waves; select is a set-min,
            //  order-independent; counts ~1-2 << 16 cap)
            #pragma unroll
            for (int mt = 0; mt < 4; ++mt)
                #pragma unroll
                for (int jj = 0; jj < 4; ++jj) {
                    int t = mt * 16 + 4 * (l >> 4) + jj;
                    float fthr = funmap(fminI[p][t]) + EPS_CAND;
                    #pragma unroll
                    for (int nf = 0; nf < 4; ++nf)
                        if (acc[mt][nf][jj] <= fthr) {
                            int s = atomicAdd(&candCnt[t], 1);
                            if (s < 16) candIdx[t][s] = vbase + nf * 16 + am;
                        }
                }
            // no barrier after pass-0 scan: pass-1 writes only fminI[1]/private acc;
            // Rf/cbh are read-only here; pushes are atomic and order-free
        }
        __syncthreads();   // BAR C: all candidates in before phase B

        // ---- Phase B: exact fp32-chain distance + packed (d,idx) atomic select ----
        {
            int t = tid & 63, s0 = tid >> 6;
            int nc = candCnt[t]; if (nc > 16) nc = 16;
            for (int s = s0; s < nc; s += 8) {
                int gi = candIdx[t][s];
                const float* crow = cbs + (size_t)gi * C_;
                float dot = 0.f;
                for (int c = 0; c < 256; c += 4) {
                    float4 cr = *reinterpret_cast<const float4*>(crow + c);
                    f4 rv = *reinterpret_cast<const f4*>(&Rf[t][c]);
                    dot = __fadd_rn(dot, __fmul_rn(rv[0], cr.x));
                    dot = __fadd_rn(dot, __fmul_rn(rv[1], cr.y));
                    dot = __fadd_rn(dot, __fmul_rn(rv[2], cr.z));
                    dot = __fadd_rn(dot, __fmul_rn(rv[3], cr.w));
                }
                float2 pv = cvw[st * V_ + gi];
                float cv2 = __fadd_rn(pv.x, pv.y);
                // Rnorm: identical fadd chain over strip partials (as rounds 3-13)
                float Rn = rnpart[t][0];
                #pragma unroll
                for (int k = 1; k < 8; ++k) Rn = __fadd_rn(Rn, rnpart[t][k]);
                float S = __fadd_rn(Rn, cv2);
                float d = __fsub_rn(S, 2.0f * dot);
                // lexicographic (d, idx) min == packed u64 min (fmap monotone, idx>=0)
                unsigned long long key =
                    ((unsigned long long)fmap(d) << 32) | (unsigned)gi;
                atomicMin(&best64[t], key);
            }
        }
        __syncthreads();   // BAR D: best ready
        if (tid < TPB) {
            int bi = (int)(best64[tid] & 0xFFFFFFFFull);
            bestIdx[tid] = bi;
            out[Z_ELEMS + ((size_t)b * K_ + st) * T_ + t0 + tid] = (float)bi;
            best64[tid]  = ~0ull;            // reset for next stage
            candCnt[tid] = 0;
            fminI[0][tid] = 0xFFFFFFFFu;
            fminI[1][tid] = 0xFFFFFFFFu;
        }
        __syncthreads();   // BAR E: bestIdx ready, resets done

        // ---- update: STE rounding exact (unchanged per-element chains) ----
        {
            const float* q = cbs + (size_t)bestIdx[ut] * C_ + ug * 32;
            float rn = 0.f;
            #pragma unroll
            for (int j4 = 0; j4 < 8; ++j4) {
                int c0 = ug * 32 + 4 * j4;
                float4 qv = *reinterpret_cast<const float4*>(q + 4 * j4);
                f4 rv = *reinterpret_cast<const f4*>(&Rf[ut][c0]);
                float qe[4] = { qv.x, qv.y, qv.z, qv.w };
                f4 nv;
                #pragma unroll
                for (int e = 0; e < 4; ++e) {
                    float r   = rv[e];
                    float qmr = __fsub_rn(qe[e], r);   // sg(q - r)
                    float zq  = __fadd_rn(r, qmr);     // r + sg(q - r)
                    float lt  = __fsub_rn(zq, r);      // sg(zq) - r
                    loss_acc  = fmaf(lt, lt, loss_acc);
                    float rn2 = __fsub_rn(r, zq);      // r - sg(zq)
                    nv[e] = rn2;
                    rn = fmaf(rn2, rn2, rn);
                }
                *reinterpret_cast<f4*>(&Rf[ut][c0]) = nv;
            }
            rnpart[ut][ug] = rn;
        }
        __syncthreads();   // BAR F: Rf + rnpart ready for next stage
    }

    // ---- epilogue: z_q = z - r_final ----
    {
        float* ob = out + (size_t)b * C_ * T_ + t0;
        for (int j = 0; j < 32; ++j) {
            int c = ug * 32 + j;
            ob[(size_t)c * T_ + ut] = __fsub_rn(zb[(size_t)c * T_ + ut], Rf[ut][c]);
        }
    }

    // ---- loss block-reduce -> atomicAdd (candIdx reused as scratch) ----
    __syncthreads();
    float* lred = reinterpret_cast<float*>(&candIdx[0][0]);   // 1024 floats avail
    lred[tid] = loss_acc;
    __syncthreads();
    if (tid < 256) lred[tid] += lred[tid + 256];
    __syncthreads();
    if (tid < 128) lred[tid] += lred[tid + 128];
    __syncthreads();
    if (tid < 64)  lred[tid] += lred[tid + 64];
    __syncthreads();
    if (tid == 0) {
        float s = 0.f;
        for (int i = 0; i < 64; ++i) s += lred[i];
        atomicAdd(out + LOSS_OFF, s * (1.0f / 67108864.0f));  // / (B*T*C) / K
    }
}

extern "C" void kernel_launch(void* const* d_in, const int* in_sizes, int n_in,
                              void* d_out, int out_size, void* d_ws, size_t ws_size,
                              hipStream_t stream)
{
    const float* z  = (const float*)d_in[0];
    const float* cb = (const float*)d_in[1];
    float* out = (float*)d_out;
    float2*    cvw = (float2*)d_ws;                              // 32 KB
    _Float16*  cbh = (_Float16*)((char*)d_ws + 32768);           // 2 MB

    rvq_zero_loss<<<1, 1, 0, stream>>>(out);
    rvq_cvnorm<<<16, 256, 0, stream>>>(cb, cvw);
    rvq_cbf16<<<512, 256, 0, stream>>>(cb, cbh);
    rvq_main<<<dim3(1024), dim3(512), 0, stream>>>(z, cb, cvw, cbh, out);
}

// Round 16
// 407.918 us; speedup vs baseline: 1.2473x; 1.0011x over previous
//
#include <hip/hip_runtime.h>
#include <math.h>

// Problem constants
#define B_   16
#define C_   256
#define T_   4096
#define V_   1024
#define K_   4
#define TPB  64      // tokens per block
#define RFP  260     // padded Rf row stride (floats); 1040 B, 16B-aligned, bank-spread
#define EPS_CAND 2e-4f

constexpr int Z_ELEMS   = B_ * C_ * T_;        // 16777216
constexpr int IDX_ELEMS = B_ * K_ * T_;        // 262144
constexpr int LOSS_OFF  = Z_ELEMS + IDX_ELEMS; // 17039360

typedef _Float16 h8 __attribute__((ext_vector_type(8)));
typedef __fp16   g2 __attribute__((ext_vector_type(2)));   // cvt_pkrtz return type
typedef float    f4 __attribute__((ext_vector_type(4)));

// monotone float<->uint order map (works for ALL floats incl. negatives):
// a < b  <=>  fmap(a) < fmap(b) (unsigned)
__device__ __forceinline__ unsigned fmap(float x) {
    unsigned u = __float_as_uint(x);
    return (u & 0x80000000u) ? ~u : (u | 0x80000000u);
}
__device__ __forceinline__ float funmap(unsigned u) {
    return (u & 0x80000000u) ? __uint_as_float(u & 0x7fffffffu) : __uint_as_float(~u);
}

__global__ void rvq_zero_loss(float* out) { out[LOSS_OFF] = 0.0f; }

// ||c||^2 partials, bit-identical chains to rounds 1-15:
// part0 = fma chain over c = 0..63 then 128..191
// part1 = fma chain over c = 64..127 then 192..255
__global__ void rvq_cvnorm(const float* __restrict__ cb, float2* __restrict__ cvw)
{
    int g = blockIdx.x * 256 + threadIdx.x;   // 0..4095 = st*1024 + v
    const float* row = cb + (size_t)g * C_;
    float p0 = 0.f, p1 = 0.f;
    for (int c = 0;   c < 64;  ++c) p0 = fmaf(row[c], row[c], p0);
    for (int c = 128; c < 192; ++c) p0 = fmaf(row[c], row[c], p0);
    for (int c = 64;  c < 128; ++c) p1 = fmaf(row[c], row[c], p1);
    for (int c = 192; c < 256; ++c) p1 = fmaf(row[c], row[c], p1);
    cvw[g] = make_float2(p0, p1);
}

// Codebook -> f16 B-fragments for mfma_f32_16x16x32_f16 (scaled by 16, RN).
// lane l, elem i of tile nt, k-step ks = B[k=ks*32+(l>>4)*8+i][n=nt*16+(l&15)]
// flat h8 index: ((st*64 + nt)*8 + ks)*64 + l
__global__ void rvq_cbf16(const float* __restrict__ cb, _Float16* __restrict__ cbh)
{
    int gid = blockIdx.x * 256 + threadIdx.x;   // 131072 h8 quads
    int l  = gid & 63;
    int ks = (gid >> 6) & 7;
    int nt = (gid >> 9) & 63;
    int st = gid >> 15;
    int v  = nt * 16 + (l & 15);
    int k  = ks * 32 + (l >> 4) * 8;
    const float* src = cb + ((size_t)(st * V_ + v)) * C_ + k;
    float4 c0 = *reinterpret_cast<const float4*>(src);
    float4 c1 = *reinterpret_cast<const float4*>(src + 4);
    h8 o;
    o[0] = (_Float16)(c0.x * 16.0f);
    o[1] = (_Float16)(c0.y * 16.0f);
    o[2] = (_Float16)(c0.z * 16.0f);
    o[3] = (_Float16)(c0.w * 16.0f);
    o[4] = (_Float16)(c1.x * 16.0f);
    o[5] = (_Float16)(c1.y * 16.0f);
    o[6] = (_Float16)(c1.z * 16.0f);
    o[7] = (_Float16)(c1.w * 16.0f);
    reinterpret_cast<h8*>(cbh)[gid] = o;
}

__launch_bounds__(512, 4)
__global__ void rvq_main(const float* __restrict__ z,
                         const float* __restrict__ cb,
                         const float2* __restrict__ cvw,
                         const _Float16* __restrict__ cbh,
                         float* __restrict__ out)
{
    __shared__ float    Rf[TPB][RFP];        // residual fp32, TOKEN-major (66.56 KB)
    __shared__ int      candIdx[TPB][16];    // candidate lists (4 KB); loss scratch at end
    __shared__ float    rnpart[TPB][8];      // ||r||^2 strip partials (2 KB)
    __shared__ unsigned fminI[2][TPB];       // per-pass mapped approx-min (0.5 KB)
    __shared__ unsigned long long best64[TPB]; // packed (d,idx) select (0.5 KB)
    __shared__ int      candCnt[TPB];
    __shared__ int      bestIdx[TPB];

    const int tid = threadIdx.x;           // 0..511
    const int blk = blockIdx.x;
    const int b   = blk >> 6;
    const int t0  = (blk & 63) * TPB;

    const int w   = tid >> 6;              // wave id = vector stripe (64 vec per pass)
    const int l   = tid & 63;              // lane
    const int ut  = tid & 63;              // update-phase token
    const int ug  = tid >> 6;              // update-phase c-strip (8 x 32)

    const int am   = l & 15;               // m/n within 16-tile
    const int akof = (l >> 4) * 8;         // k sub-block offset (K=32 frag)

    // ---- stage residual tile (token-major fp32) ----
    const float* zb = z + (size_t)b * C_ * T_ + t0;
    for (int j = 0; j < 32; ++j) {
        int c = ug * 32 + j;
        Rf[ut][c] = zb[(size_t)c * T_ + ut];
    }
    __syncthreads();
    // ---- rnpart init (identical chains to rounds 3-15) ----
    {
        float p = 0.f;
        for (int j = 0; j < 32; ++j) { float r = Rf[ut][ug * 32 + j]; p = fmaf(r, r, p); }
        rnpart[ut][ug] = p;
    }
    if (tid < TPB) {
        candCnt[tid] = 0;
        best64[tid]  = ~0ull;
        fminI[0][tid] = 0xFFFFFFFFu;
        fminI[1][tid] = 0xFFFFFFFFu;
    }
    __syncthreads();

    float loss_acc = 0.f;

    for (int st = 0; st < K_; ++st) {
        const float* cbs = cb + (size_t)st * V_ * C_;

        // ======== two N-passes; each wave covers 64 tok x 64 vec ========
        for (int p = 0; p < 2; ++p) {
            const int vbase = p * 512 + w * 64;

            f4 acc[4][4];
            #pragma unroll
            for (int mt = 0; mt < 4; ++mt)
                #pragma unroll
                for (int nf = 0; nf < 4; ++nf)
                    acc[mt][nf] = (f4){0.f, 0.f, 0.f, 0.f};

            {
                const h8* cbh8 = reinterpret_cast<const h8*>(cbh);
                const size_t wbase = (size_t)(st * 64 + (vbase >> 4)) * 512 + l;
                #pragma unroll 2
                for (int ks = 0; ks < 8; ++ks) {
                    const int k0 = ks * 32 + akof;
                    h8 af[4];
                    #pragma unroll
                    for (int mt = 0; mt < 4; ++mt) {
                        const int m = mt * 16 + am;
                        f4 x = *reinterpret_cast<const f4*>(&Rf[m][k0]);
                        f4 y = *reinterpret_cast<const f4*>(&Rf[m][k0 + 4]);
                        // RTZ pack-convert: filter-only (phase B exact); EPS margin ~6x.
                        // Index-bit-exactness validated in r12/r14 passing runs.
                        union { h8 v; g2 pk[4]; } u;
                        u.pk[0] = __builtin_amdgcn_cvt_pkrtz(x[0], x[1]);
                        u.pk[1] = __builtin_amdgcn_cvt_pkrtz(x[2], x[3]);
                        u.pk[2] = __builtin_amdgcn_cvt_pkrtz(y[0], y[1]);
                        u.pk[3] = __builtin_amdgcn_cvt_pkrtz(y[2], y[3]);
                        af[mt] = u.v;
                    }
                    #pragma unroll
                    for (int nf = 0; nf < 4; ++nf) {
                        h8 bf = cbh8[wbase + (size_t)nf * 512 + ks * 64];
                        #pragma unroll
                        for (int mt = 0; mt < 4; ++mt)
                            acc[mt][nf] = __builtin_amdgcn_mfma_f32_16x16x32_f16(af[mt], bf, acc[mt][nf], 0, 0, 0);
                    }
                }
            }

            // ---- approx distances d' = cv2 - 0.125*acc ----
            #pragma unroll
            for (int nf = 0; nf < 4; ++nf) {
                int v = vbase + nf * 16 + am;
                float2 pv = cvw[st * V_ + v];
                float cv2 = __fadd_rn(pv.x, pv.y);
                #pragma unroll
                for (int mt = 0; mt < 4; ++mt)
                    #pragma unroll
                    for (int jj = 0; jj < 4; ++jj)
                        acc[mt][nf][jj] = fmaf(acc[mt][nf][jj], -0.125f, cv2);
            }

            // ---- per-wave per-token min -> LDS atomicMin (exact; min has no rounding) ----
            #pragma unroll
            for (int mt = 0; mt < 4; ++mt)
                #pragma unroll
                for (int jj = 0; jj < 4; ++jj) {
                    float m0 = acc[mt][0][jj];
                    #pragma unroll
                    for (int nf = 1; nf < 4; ++nf) m0 = fminf(m0, acc[mt][nf][jj]);
                    m0 = fminf(m0, __shfl_xor(m0, 1, 16));
                    m0 = fminf(m0, __shfl_xor(m0, 2, 16));
                    m0 = fminf(m0, __shfl_xor(m0, 4, 16));
                    m0 = fminf(m0, __shfl_xor(m0, 8, 16));
                    if (am == 0)
                        atomicMin(&fminI[p][mt * 16 + 4 * (l >> 4) + jj], fmap(m0));
                }
            __syncthreads();   // BAR A/B: fminI[p] complete across waves

            // ---- candidate scan & push (pass-local min window; superset) ----
            #pragma unroll
            for (int mt = 0; mt < 4; ++mt)
                #pragma unroll
                for (int jj = 0; jj < 4; ++jj) {
                    int t = mt * 16 + 4 * (l >> 4) + jj;
                    float fthr = funmap(fminI[p][t]) + EPS_CAND;
                    #pragma unroll
                    for (int nf = 0; nf < 4; ++nf)
                        if (acc[mt][nf][jj] <= fthr) {
                            int s = atomicAdd(&candCnt[t], 1);
                            if (s < 16) candIdx[t][s] = vbase + nf * 16 + am;
                        }
                }
            // no barrier after pass-0 scan: pass-1 writes only fminI[1]/private acc;
            // Rf/cbh are read-only here; pushes are atomic and order-free
        }
        __syncthreads();   // BAR C: all candidates in before phase B

        // ---- Phase B: exact fp32-chain distance + packed (d,idx) atomic select ----
        {
            int t = tid & 63, s0 = tid >> 6;
            int nc = candCnt[t]; if (nc > 16) nc = 16;
            for (int s = s0; s < nc; s += 8) {
                int gi = candIdx[t][s];
                const float* crow = cbs + (size_t)gi * C_;
                float dot = 0.f;
                for (int c = 0; c < 256; c += 4) {
                    float4 cr = *reinterpret_cast<const float4*>(crow + c);
                    f4 rv = *reinterpret_cast<const f4*>(&Rf[t][c]);
                    dot = __fadd_rn(dot, __fmul_rn(rv[0], cr.x));
                    dot = __fadd_rn(dot, __fmul_rn(rv[1], cr.y));
                    dot = __fadd_rn(dot, __fmul_rn(rv[2], cr.z));
                    dot = __fadd_rn(dot, __fmul_rn(rv[3], cr.w));
                }
                float2 pv = cvw[st * V_ + gi];
                float cv2 = __fadd_rn(pv.x, pv.y);
                // Rnorm: identical fadd chain over strip partials (as rounds 3-15)
                float Rn = rnpart[t][0];
                #pragma unroll
                for (int k = 1; k < 8; ++k) Rn = __fadd_rn(Rn, rnpart[t][k]);
                float S = __fadd_rn(Rn, cv2);
                float d = __fsub_rn(S, 2.0f * dot);
                // lexicographic (d, idx) min == packed u64 min (fmap monotone, idx>=0)
                unsigned long long key =
                    ((unsigned long long)fmap(d) << 32) | (unsigned)gi;
                atomicMin(&best64[t], key);
            }
        }
        __syncthreads();   // BAR D: best ready
        if (tid < TPB) {
            int bi = (int)(best64[tid] & 0xFFFFFFFFull);
            bestIdx[tid] = bi;
            out[Z_ELEMS + ((size_t)b * K_ + st) * T_ + t0 + tid] = (float)bi;
            best64[tid]  = ~0ull;            // reset for next stage
            candCnt[tid] = 0;
            fminI[0][tid] = 0xFFFFFFFFu;
            fminI[1][tid] = 0xFFFFFFFFu;
        }
        __syncthreads();   // BAR E: bestIdx ready, resets done

        // ---- update: STE rounding exact (unchanged per-element chains) ----
        {
            const float* q = cbs + (size_t)bestIdx[ut] * C_ + ug * 32;
            float rn = 0.f;
            #pragma unroll
            for (int j4 = 0; j4 < 8; ++j4) {
                int c0 = ug * 32 + 4 * j4;
                float4 qv = *reinterpret_cast<const float4*>(q + 4 * j4);
                f4 rv = *reinterpret_cast<const f4*>(&Rf[ut][c0]);
                float qe[4] = { qv.x, qv.y, qv.z, qv.w };
                f4 nv;
                #pragma unroll
                for (int e = 0; e < 4; ++e) {
                    float r   = rv[e];
                    float qmr = __fsub_rn(qe[e], r);   // sg(q - r)
                    float zq  = __fadd_rn(r, qmr);     // r + sg(q - r)
                    float lt  = __fsub_rn(zq, r);      // sg(zq) - r
                    loss_acc  = fmaf(lt, lt, loss_acc);
                    float rn2 = __fsub_rn(r, zq);      // r - sg(zq)
                    nv[e] = rn2;
                    rn = fmaf(rn2, rn2, rn);
                }
                *reinterpret_cast<f4*>(&Rf[ut][c0]) = nv;
            }
            rnpart[ut][ug] = rn;
        }
        __syncthreads();   // BAR F: Rf + rnpart ready for next stage
    }

    // ---- epilogue: z_q = z - r_final ----
    {
        float* ob = out + (size_t)b * C_ * T_ + t0;
        for (int j = 0; j < 32; ++j) {
            int c = ug * 32 + j;
            ob[(size_t)c * T_ + ut] = __fsub_rn(zb[(size_t)c * T_ + ut], Rf[ut][c]);
        }
    }

    // ---- loss block-reduce -> atomicAdd (candIdx reused as scratch) ----
    __syncthreads();
    float* lred = reinterpret_cast<float*>(&candIdx[0][0]);   // 1024 floats avail
    lred[tid] = loss_acc;
    __syncthreads();
    if (tid < 256) lred[tid] += lred[tid + 256];
    __syncthreads();
    if (tid < 128) lred[tid] += lred[tid + 128];
    __syncthreads();
    if (tid < 64)  lred[tid] += lred[tid + 64];
    __syncthreads();
    if (tid == 0) {
        float s = 0.f;
        for (int i = 0; i < 64; ++i) s += lred[i];
        atomicAdd(out + LOSS_OFF, s * (1.0f / 67108864.0f));  // / (B*T*C) / K
    }
}

extern "C" void kernel_launch(void* const* d_in, const int* in_sizes, int n_in,
                              void* d_out, int out_size, void* d_ws, size_t ws_size,
                              hipStream_t stream)
{
    const float* z  = (const float*)d_in[0];
    const float* cb = (const float*)d_in[1];
    float* out = (float*)d_out;
    float2*    cvw = (float2*)d_ws;                              // 32 KB
    _Float16*  cbh = (_Float16*)((char*)d_ws + 32768);           // 2 MB

    rvq_zero_loss<<<1, 1, 0, stream>>>(out);
    rvq_cvnorm<<<16, 256, 0, stream>>>(cb, cvw);
    rvq_cbf16<<<512, 256, 0, stream>>>(cb, cbh);
    rvq_main<<<dim3(1024), dim3(512), 0, stream>>>(z, cb, cvw, cbh, out);
}